// Round 6
// baseline (257.287 us; speedup 1.0000x reference)
//
#include <hip/hip_runtime.h>
#include <hip/hip_bf16.h>

typedef __attribute__((ext_vector_type(8))) short short8;
typedef __attribute__((ext_vector_type(4))) short short4v;
typedef __attribute__((ext_vector_type(4))) float f32x4;
typedef __attribute__((ext_vector_type(16))) float f32x16;
typedef __attribute__((ext_vector_type(4))) unsigned int u32x4;
typedef unsigned short u16;

__device__ __forceinline__ u16 f2bf(float f) {
  __hip_bfloat16 h = __float2bfloat16(f);
  return __builtin_bit_cast(unsigned short, h);
}

__device__ __forceinline__ unsigned pack2(float lo, float hi) {
  return (unsigned)f2bf(lo) | ((unsigned)f2bf(hi) << 16);
}

__device__ __forceinline__ void gload16(const u16* g, u16* l) {
  __builtin_amdgcn_global_load_lds(
      (const __attribute__((address_space(1))) unsigned int*)g,
      (__attribute__((address_space(3))) unsigned int*)l, 16, 0, 0);
}

// ---------- x fp32 -> bf16 ----------
__global__ void cvt_x_kernel(const float* __restrict__ in, u16* __restrict__ out, int n) {
  int i = (blockIdx.x * blockDim.x + threadIdx.x) * 4;
  if (i >= n) return;
  float4 f = *(const float4*)(in + i);
  uint2 pk;
  pk.x = pack2(f.x, f.y);
  pk.y = pack2(f.z, f.w);
  *(uint2*)(out + i) = pk;
}

// ---------- W [1024][N] fp32 -> Wt [N][1024] bf16 ----------
__global__ void tcvt_kernel(const float* __restrict__ in, u16* __restrict__ out, int N) {
  __shared__ float tile[32][33];
  int n0 = blockIdx.x * 32, k0 = blockIdx.y * 32;
  int tx = threadIdx.x, ty = threadIdx.y;  // 32 x 8
#pragma unroll
  for (int r = 0; r < 4; ++r) {
    int k = ty + r * 8;
    tile[k][tx] = in[(size_t)(k0 + k) * N + n0 + tx];
  }
  __syncthreads();
#pragma unroll
  for (int r = 0; r < 4; ++r) {
    int n = ty + r * 8;
    out[(size_t)(n0 + n) * 1024 + k0 + tx] = f2bf(tile[tx][n]);
  }
}

// ---------- GEMM: C[128x128 tile] = A[M][1024] * Bt[N][1024]^T + bias ----------
// EPI 0: Q,K -> bf16 [b,h,s,64] (Q scaled by 0.125*log2e); V -> TRANSPOSED [b,h,hd,s]
// EPI 1: fp32 out [4096][1024] + bias
template <int EPI>
__global__ __launch_bounds__(256, 2) void gemm_kernel(const u16* __restrict__ A,
                                                      const u16* __restrict__ Bt,
                                                      const float* __restrict__ bias,
                                                      void* __restrict__ outp) {
  __shared__ u16 Al[128 * 64];
  __shared__ u16 Bl[128 * 64];
  const int tid = threadIdx.x;
  const int lane = tid & 63, wid = tid >> 6;
  const int l15 = lane & 15, lg = lane >> 4;
  const int wm = wid >> 1, wn = wid & 1;
  const int m0 = blockIdx.y * 128, n0 = blockIdx.x * 128;

  f32x4 acc[4][4] = {};

  for (int k0 = 0; k0 < 1024; k0 += 64) {
    __syncthreads();
#pragma unroll
    for (int i = 0; i < 4; ++i) {
      int p = i * 4096 + tid * 16;
      int row = p >> 7;
      int lslot = ((p >> 4) & 7) ^ (row & 7);
      gload16(A + (size_t)(m0 + row) * 1024 + k0 + lslot * 8, Al + i * 2048 + wid * 512);
      gload16(Bt + (size_t)(n0 + row) * 1024 + k0 + lslot * 8, Bl + i * 2048 + wid * 512);
    }
    __syncthreads();
#pragma unroll
    for (int ks = 0; ks < 2; ++ks) {
      short8 af[4], bfr[4];
#pragma unroll
      for (int m = 0; m < 4; ++m) {
        int row = wm * 64 + m * 16 + l15;
        af[m] = *(const short8*)((const char*)Al + row * 128 + (((ks * 4 + lg) ^ (row & 7)) << 4));
      }
#pragma unroll
      for (int n = 0; n < 4; ++n) {
        int row = wn * 64 + n * 16 + l15;
        bfr[n] = *(const short8*)((const char*)Bl + row * 128 + (((ks * 4 + lg) ^ (row & 7)) << 4));
      }
#pragma unroll
      for (int m = 0; m < 4; ++m)
#pragma unroll
        for (int n = 0; n < 4; ++n)
          acc[m][n] = __builtin_amdgcn_mfma_f32_16x16x32_bf16(af[m], bfr[n], acc[m][n], 0, 0, 0);
    }
  }

  if (EPI == 0) {
    u16* qkv = (u16*)outp;
#pragma unroll
    for (int m = 0; m < 4; ++m)
#pragma unroll
      for (int n = 0; n < 4; ++n) {
        const int gcol = n0 + wn * 64 + n * 16 + l15;
        const int which = gcol >> 10, dd = gcol & 1023;
        const int h = dd >> 6, hd = dd & 63;
        const float bb = bias[gcol];
        const int grow0 = m0 + wm * 64 + m * 16 + lg * 4;
        const int b = grow0 >> 11, s0 = grow0 & 2047;
        if (which == 2) {
          // V: store transposed [b,h,hd,s] — 4 consecutive s -> one 8B store
          short4v pk;
#pragma unroll
          for (int j = 0; j < 4; ++j) pk[j] = (short)f2bf(acc[m][n][j] + bb);
          *(short4v*)(qkv + (size_t)2 * 4194304 + ((size_t)(b * 16 + h) * 64 + hd) * 2048 + s0) = pk;
        } else {
          const float sc = (which == 0) ? 0.18033688011112042f : 1.0f;  // 1/sqrt(64)*log2e on Q
#pragma unroll
          for (int j = 0; j < 4; ++j) {
            float v = (acc[m][n][j] + bb) * sc;
            qkv[(size_t)which * 4194304 + ((size_t)(b * 16 + h) * 2048 + s0 + j) * 64 + hd] = f2bf(v);
          }
        }
      }
  } else {
    float* O = (float*)outp;
#pragma unroll
    for (int m = 0; m < 4; ++m)
#pragma unroll
      for (int n = 0; n < 4; ++n) {
        const int gcol = n0 + wn * 64 + n * 16 + l15;
        const float bb = bias[gcol];
#pragma unroll
        for (int j = 0; j < 4; ++j) {
          const int grow = m0 + wm * 64 + m * 16 + lg * 4 + j;
          O[(size_t)grow * 1024 + gcol] = acc[m][n][j] + bb;
        }
      }
  }
}

// ---------- causal flash attention, 32x32 MFMA, swapped QK^T, in-register P ----------
// Grid (16, 32). Block = 256 threads (4 waves). Block p handles 64-row q-tiles
// p and 31-p (complement pairing). Wave (qs=wid&1, kp=wid>>1): q-strip
// tile*64+qs*32 of BOTH tiles, kv-subtile parity kp of each staged 64-kv tile.
// Each wave keeps an independent online-softmax partial over its kv class;
// partials merged at the end via LDS (flash combine). -> 4 waves/SIMD.
// S^T = mfma(K,Q): lane holds q = q0+(lane&31), 16 kv per subtile in regs.
// Softmax in-lane; P->PV B-operand via pack + shfl_xor(32) (T12).
// K and V^T staged via global_load_lds (V pre-transposed by QKV epilogue),
// double-buffered, prefetch issued before compute (T14).
__global__ __launch_bounds__(256, 4) void attn_kernel(const u16* __restrict__ Q,
                                                      const u16* __restrict__ K,
                                                      const u16* __restrict__ VT,
                                                      u16* __restrict__ Aout) {
  const int bh = blockIdx.y;   // 0..31
  const int p = blockIdx.x;    // 0..15 -> pair (p, 31-p)
  const int tid = threadIdx.x, lane = tid & 63, wid = tid >> 6;
  const int l31 = lane & 31, h = lane >> 5;
  const int qs = wid & 1, kp = wid >> 1;

  __shared__ __align__(16) char smem[36864];
  u16(*Kl)[4096] = (u16(*)[4096])smem;             // [2][64*64] kv x hd, swizzled
  u16(*Vl)[4096] = (u16(*)[4096])(smem + 16384);   // [2][64*64] hd x kv, swizzled

  const u16* Qb = Q + (size_t)bh * 2048 * 64;
  const u16* Kb = K + (size_t)bh * 2048 * 64;
  const u16* Vb = VT + (size_t)bh * 64 * 2048;     // V^T: [hd][s]

  const int qA = p * 64 + qs * 32;
  const int qB = (31 - p) * 64 + qs * 32;
  const int R = 32 - p;  // kv tiles for the heavy member

  short8 qfA[4], qfB[4];
#pragma unroll
  for (int ks = 0; ks < 4; ++ks) {
    qfA[ks] = *(const short8*)(Qb + (size_t)(qA + l31) * 64 + ks * 16 + h * 8);
    qfB[ks] = *(const short8*)(Qb + (size_t)(qB + l31) * 64 + ks * 16 + h * 8);
  }

  f32x16 accA[2] = {}, accB[2] = {};
  float mA = -1e30f, mB = -1e30f, lA = 0.f, lB = 0.f;

  // staging: 256 threads x 16B covers half a tile per pass (2 passes K, 2 V)
  auto stage = [&](int buf, size_t kb) {
#pragma unroll
    for (int i = 0; i < 2; ++i) {
      const int row = i * 32 + (tid >> 3);
      const int sc = ((tid & 7) ^ (row & 7)) * 8;
      gload16(Kb + (kb + row) * 64 + sc, &Kl[buf][i * 2048 + wid * 512]);
      gload16(Vb + (size_t)row * 2048 + kb + sc, &Vl[buf][i * 2048 + wid * 512]);
    }
  };

  stage(0, 0);
  __syncthreads();

  for (int t = 0; t < R; ++t) {
    const int cur = t & 1;
    if (t + 1 < R) stage(cur ^ 1, (size_t)(t + 1) * 64);  // prefetch (T14)

    const int kvbase = t * 64 + kp * 32;
    const bool actB = kvbase <= qB + 31;
    const bool actA = kvbase <= qA + 31;  // actA implies actB (qA < qB)
    if (actB) {
      // K fragments (A-operand) and V^T fragments for this wave's kv sub
      short8 kf[4], vf[2][2];
      const int krow = kp * 32 + l31;
#pragma unroll
      for (int ks = 0; ks < 4; ++ks)
        kf[ks] = *(const short8*)((const char*)&Kl[cur][0] + krow * 128 +
                                  (((ks * 2 + h) ^ (krow & 7)) << 4));
#pragma unroll
      for (int n = 0; n < 2; ++n)
#pragma unroll
        for (int ks = 0; ks < 2; ++ks) {
          const int row = n * 32 + l31;
          vf[n][ks] = *(const short8*)((const char*)&Vl[cur][0] + row * 128 +
                                       (((kp * 4 + ks * 2 + h) ^ (row & 7)) << 4));
        }

      auto strip = [&](const short8(&qf)[4], f32x16(&acc)[2], float& m, float& l, int q0) {
        f32x16 sa = {};
#pragma unroll
        for (int ks = 0; ks < 4; ++ks)
          sa = __builtin_amdgcn_mfma_f32_32x32x16_bf16(kf[ks], qf[ks], sa, 0, 0, 0);
        if (kvbase == q0) {  // diagonal subtile
#pragma unroll
          for (int r = 0; r < 16; ++r) {
            const int kvr = (r & 3) + 8 * (r >> 2) + 4 * h;
            if (kvr > l31) sa[r] = -1e30f;
          }
        }
        float rm = fmaxf(fmaxf(fmaxf(sa[0], sa[1]), fmaxf(sa[2], sa[3])),
                         fmaxf(fmaxf(sa[4], sa[5]), fmaxf(sa[6], sa[7])));
        rm = fmaxf(rm, fmaxf(fmaxf(fmaxf(sa[8], sa[9]), fmaxf(sa[10], sa[11])),
                             fmaxf(fmaxf(sa[12], sa[13]), fmaxf(sa[14], sa[15]))));
        rm = fmaxf(rm, __shfl_xor(rm, 32));
        if (!__all(rm <= m + 5.0f)) {  // T13 defer-max (log2 units)
          const float mn = fmaxf(m, rm);
          const float corr = exp2f(m - mn);
          m = mn;
          l *= corr;
#pragma unroll
          for (int n = 0; n < 2; ++n)
#pragma unroll
            for (int r = 0; r < 16; ++r) acc[n][r] *= corr;
        }
#pragma unroll
        for (int r = 0; r < 16; ++r) sa[r] = exp2f(sa[r] - m);
        // row-sum (16 in-lane + cross-half partner has same q)
        float rs = (((sa[0] + sa[1]) + (sa[2] + sa[3])) + ((sa[4] + sa[5]) + (sa[6] + sa[7]))) +
                   (((sa[8] + sa[9]) + (sa[10] + sa[11])) + ((sa[12] + sa[13]) + (sa[14] + sa[15])));
        l += rs + __shfl_xor(rs, 32);
        // pack P^T pairs; build B-operand frags via cross-half exchange (T12)
        unsigned c[8], s[8];
#pragma unroll
        for (int i = 0; i < 8; ++i) c[i] = pack2(sa[2 * i], sa[2 * i + 1]);
#pragma unroll
        for (int i = 0; i < 8; ++i) s[i] = __shfl_xor(c[i], 32);
        u32x4 w0, w1;
        if (h == 0) {
          w0 = (u32x4){c[0], c[1], s[0], s[1]};
          w1 = (u32x4){c[4], c[5], s[4], s[5]};
        } else {
          w0 = (u32x4){s[2], s[3], c[2], c[3]};
          w1 = (u32x4){s[6], s[7], c[6], c[7]};
        }
        const short8 pk0 = __builtin_bit_cast(short8, w0);
        const short8 pk1 = __builtin_bit_cast(short8, w1);
#pragma unroll
        for (int n = 0; n < 2; ++n) {
          acc[n] = __builtin_amdgcn_mfma_f32_32x32x16_bf16(vf[n][0], pk0, acc[n], 0, 0, 0);
          acc[n] = __builtin_amdgcn_mfma_f32_32x32x16_bf16(vf[n][1], pk1, acc[n], 0, 0, 0);
        }
      };

      strip(qfB, accB, mB, lB, qB);
      if (actA) strip(qfA, accA, mA, lA, qA);
    }
    __syncthreads();
  }

  // ---- merge kv-parity partials (flash combine) and store ----
  // comb layout: [qs][strip][lane][36 floats]  (36*4=144B stride, 16B aligned)
  float* comb = (float*)smem;
  float* pA = comb + ((qs * 2 + 0) * 64 + lane) * 36;
  float* pB = comb + ((qs * 2 + 1) * 64 + lane) * 36;
  if (kp == 1) {
    pA[0] = mA; pA[1] = lA;
    pB[0] = mB; pB[1] = lB;
#pragma unroll
    for (int n = 0; n < 2; ++n)
#pragma unroll
      for (int r = 0; r < 16; ++r) {
        pA[2 + n * 16 + r] = accA[n][r];
        pB[2 + n * 16 + r] = accB[n][r];
      }
  }
  __syncthreads();
  if (kp == 0) {
    const int b = bh >> 4, hh = bh & 15;
    auto merge_store = [&](const float* pp, const f32x16(&acc)[2], float m0, float l0, int q0) {
      const float m1 = pp[0], l1 = pp[1];
      const float mn = fmaxf(m0, m1);
      const float c0 = exp2f(m0 - mn), c1 = exp2f(m1 - mn);
      const float inv = 1.0f / (l0 * c0 + l1 * c1);
      u16* rowp = Aout + (size_t)(b * 2048 + q0 + l31) * 1024 + hh * 64;
#pragma unroll
      for (int n = 0; n < 2; ++n)
#pragma unroll
        for (int r = 0; r < 16; r += 2) {
          const int hd = n * 32 + (r & 3) + 8 * (r >> 2) + 4 * h;
          const float v0 = (acc[n][r] * c0 + pp[2 + n * 16 + r] * c1) * inv;
          const float v1 = (acc[n][r + 1] * c0 + pp[2 + n * 16 + r + 1] * c1) * inv;
          *(unsigned*)(rowp + hd) = pack2(v0, v1);
        }
    };
    merge_store(pA, accA, mA, lA, qA);
    merge_store(pB, accB, mB, lB, qB);
  }
}

extern "C" void kernel_launch(void* const* d_in, const int* in_sizes, int n_in,
                              void* d_out, int out_size, void* d_ws, size_t ws_size,
                              hipStream_t stream) {
  const float* x = (const float*)d_in[0];
  const float* Wqkv = (const float*)d_in[1];
  const float* bqkv = (const float*)d_in[2];
  const float* Wout = (const float*)d_in[3];
  const float* bout = (const float*)d_in[4];

  char* ws = (char*)d_ws;
  u16* Xb = (u16*)(ws + 0);            // 8,388,608 B  (reused as Attn later)
  u16* WqkvT = (u16*)(ws + 8388608);   // 6,291,456 B
  u16* WoutT = (u16*)(ws + 14680064);  // 2,097,152 B
  u16* QKV = (u16*)(ws + 16777216);    // 25,165,824 B (Q, K, V^T)
  u16* Attn = Xb;

  cvt_x_kernel<<<4096, 256, 0, stream>>>(x, Xb, 4194304);
  tcvt_kernel<<<dim3(96, 32), dim3(32, 8), 0, stream>>>(Wqkv, WqkvT, 3072);
  tcvt_kernel<<<dim3(32, 32), dim3(32, 8), 0, stream>>>(Wout, WoutT, 1024);
  gemm_kernel<0><<<dim3(24, 32), 256, 0, stream>>>(Xb, WqkvT, bqkv, QKV);
  attn_kernel<<<dim3(16, 32), 256, 0, stream>>>(QKV, QKV + 4194304, QKV + 8388608, Attn);
  gemm_kernel<1><<<dim3(8, 32), 256, 0, stream>>>(Attn, WoutT, bout, d_out);
}

// Round 7
// 113.049 us; speedup vs baseline: 2.2759x; 2.2759x over previous
//
#include <hip/hip_runtime.h>
#include <hip/hip_bf16.h>

typedef __attribute__((ext_vector_type(8))) short short8;
typedef __attribute__((ext_vector_type(4))) short short4v;
typedef __attribute__((ext_vector_type(4))) float f32x4;
typedef __attribute__((ext_vector_type(16))) float f32x16;
typedef __attribute__((ext_vector_type(4))) unsigned int u32x4;
typedef unsigned short u16;

__device__ __forceinline__ u16 f2bf(float f) {
  __hip_bfloat16 h = __float2bfloat16(f);
  return __builtin_bit_cast(unsigned short, h);
}

__device__ __forceinline__ unsigned pack2(float lo, float hi) {
  return (unsigned)f2bf(lo) | ((unsigned)f2bf(hi) << 16);
}

__device__ __forceinline__ void gload16(const u16* g, u16* l) {
  __builtin_amdgcn_global_load_lds(
      (const __attribute__((address_space(1))) unsigned int*)g,
      (__attribute__((address_space(3))) unsigned int*)l, 16, 0, 0);
}

// ---------- x fp32 -> bf16 ----------
__global__ void cvt_x_kernel(const float* __restrict__ in, u16* __restrict__ out, int n) {
  int i = (blockIdx.x * blockDim.x + threadIdx.x) * 4;
  if (i >= n) return;
  float4 f = *(const float4*)(in + i);
  uint2 pk;
  pk.x = pack2(f.x, f.y);
  pk.y = pack2(f.z, f.w);
  *(uint2*)(out + i) = pk;
}

// ---------- W [1024][N] fp32 -> Wt [N][1024] bf16 ----------
__global__ void tcvt_kernel(const float* __restrict__ in, u16* __restrict__ out, int N) {
  __shared__ float tile[32][33];
  int n0 = blockIdx.x * 32, k0 = blockIdx.y * 32;
  int tx = threadIdx.x, ty = threadIdx.y;  // 32 x 8
#pragma unroll
  for (int r = 0; r < 4; ++r) {
    int k = ty + r * 8;
    tile[k][tx] = in[(size_t)(k0 + k) * N + n0 + tx];
  }
  __syncthreads();
#pragma unroll
  for (int r = 0; r < 4; ++r) {
    int n = ty + r * 8;
    out[(size_t)(n0 + n) * 1024 + k0 + tx] = f2bf(tile[tx][n]);
  }
}

// ---------- GEMM: C[128x128 tile] = A[M][1024] * Bt[N][1024]^T + bias ----------
// EPI 0: Q,K -> bf16 [b,h,s,64] (Q scaled by 0.125*log2e); V -> TRANSPOSED [b,h,hd,s]
// EPI 1: fp32 out [4096][1024] + bias
template <int EPI>
__global__ __launch_bounds__(256, 2) void gemm_kernel(const u16* __restrict__ A,
                                                      const u16* __restrict__ Bt,
                                                      const float* __restrict__ bias,
                                                      void* __restrict__ outp) {
  __shared__ u16 Al[128 * 64];
  __shared__ u16 Bl[128 * 64];
  const int tid = threadIdx.x;
  const int lane = tid & 63, wid = tid >> 6;
  const int l15 = lane & 15, lg = lane >> 4;
  const int wm = wid >> 1, wn = wid & 1;
  const int m0 = blockIdx.y * 128, n0 = blockIdx.x * 128;

  f32x4 acc[4][4] = {};

  for (int k0 = 0; k0 < 1024; k0 += 64) {
    __syncthreads();
#pragma unroll
    for (int i = 0; i < 4; ++i) {
      int p = i * 4096 + tid * 16;
      int row = p >> 7;
      int lslot = ((p >> 4) & 7) ^ (row & 7);
      gload16(A + (size_t)(m0 + row) * 1024 + k0 + lslot * 8, Al + i * 2048 + wid * 512);
      gload16(Bt + (size_t)(n0 + row) * 1024 + k0 + lslot * 8, Bl + i * 2048 + wid * 512);
    }
    __syncthreads();
#pragma unroll
    for (int ks = 0; ks < 2; ++ks) {
      short8 af[4], bfr[4];
#pragma unroll
      for (int m = 0; m < 4; ++m) {
        int row = wm * 64 + m * 16 + l15;
        af[m] = *(const short8*)((const char*)Al + row * 128 + (((ks * 4 + lg) ^ (row & 7)) << 4));
      }
#pragma unroll
      for (int n = 0; n < 4; ++n) {
        int row = wn * 64 + n * 16 + l15;
        bfr[n] = *(const short8*)((const char*)Bl + row * 128 + (((ks * 4 + lg) ^ (row & 7)) << 4));
      }
#pragma unroll
      for (int m = 0; m < 4; ++m)
#pragma unroll
        for (int n = 0; n < 4; ++n)
          acc[m][n] = __builtin_amdgcn_mfma_f32_16x16x32_bf16(af[m], bfr[n], acc[m][n], 0, 0, 0);
    }
  }

  if (EPI == 0) {
    u16* qkv = (u16*)outp;
#pragma unroll
    for (int m = 0; m < 4; ++m)
#pragma unroll
      for (int n = 0; n < 4; ++n) {
        const int gcol = n0 + wn * 64 + n * 16 + l15;
        const int which = gcol >> 10, dd = gcol & 1023;
        const int h = dd >> 6, hd = dd & 63;
        const float bb = bias[gcol];
        const int grow0 = m0 + wm * 64 + m * 16 + lg * 4;
        const int b = grow0 >> 11, s0 = grow0 & 2047;
        if (which == 2) {
          // V: store transposed [b,h,hd,s] — 4 consecutive s -> one 8B store
          short4v pk;
#pragma unroll
          for (int j = 0; j < 4; ++j) pk[j] = (short)f2bf(acc[m][n][j] + bb);
          *(short4v*)(qkv + (size_t)2 * 4194304 + ((size_t)(b * 16 + h) * 64 + hd) * 2048 + s0) = pk;
        } else {
          const float sc = (which == 0) ? 0.18033688011112042f : 1.0f;  // 1/sqrt(64)*log2e on Q
#pragma unroll
          for (int j = 0; j < 4; ++j) {
            float v = (acc[m][n][j] + bb) * sc;
            qkv[(size_t)which * 4194304 + ((size_t)(b * 16 + h) * 2048 + s0 + j) * 64 + hd] = f2bf(v);
          }
        }
      }
  } else {
    float* O = (float*)outp;
#pragma unroll
    for (int m = 0; m < 4; ++m)
#pragma unroll
      for (int n = 0; n < 4; ++n) {
        const int gcol = n0 + wn * 64 + n * 16 + l15;
        const float bb = bias[gcol];
#pragma unroll
        for (int j = 0; j < 4; ++j) {
          const int grow = m0 + wm * 64 + m * 16 + lg * 4 + j;
          O[(size_t)grow * 1024 + gcol] = acc[m][n][j] + bb;
        }
      }
  }
}

// ---------- causal flash attention, 32x32 MFMA, swapped QK^T, in-register P ----------
// Grid (16, 32). Block = 256 threads (4 waves). Block p handles 64-row q-tiles
// p and 31-p (complement pairing). Wave (qs=wid&1, kp=wid>>1): q-strip
// tile*64+qs*32 of BOTH tiles, kv-subtile parity kp of each staged 64-kv tile.
// Each wave keeps an independent online-softmax partial over its kv class;
// partials merged at the end via LDS (flash combine).
// launch_bounds(256,2): 256-VGPR cap — (256,4) forced a 64-VGPR spill (R6).
// S^T = mfma(K,Q): lane holds q = q0+(lane&31), 16 kv per subtile in regs.
// Softmax in-lane; P->PV B-operand via pack + shfl_xor(32) (T12).
// K and V^T staged via global_load_lds (V pre-transposed by QKV epilogue),
// double-buffered, prefetch issued before compute (T14).
__global__ __launch_bounds__(256, 2) void attn_kernel(const u16* __restrict__ Q,
                                                      const u16* __restrict__ K,
                                                      const u16* __restrict__ VT,
                                                      u16* __restrict__ Aout) {
  const int bh = blockIdx.y;   // 0..31
  const int p = blockIdx.x;    // 0..15 -> pair (p, 31-p)
  const int tid = threadIdx.x, lane = tid & 63, wid = tid >> 6;
  const int l31 = lane & 31, h = lane >> 5;
  const int qs = wid & 1, kp = wid >> 1;

  __shared__ __align__(16) char smem[36864];
  u16(*Kl)[4096] = (u16(*)[4096])smem;             // [2][64*64] kv x hd, swizzled
  u16(*Vl)[4096] = (u16(*)[4096])(smem + 16384);   // [2][64*64] hd x kv, swizzled

  const u16* Qb = Q + (size_t)bh * 2048 * 64;
  const u16* Kb = K + (size_t)bh * 2048 * 64;
  const u16* Vb = VT + (size_t)bh * 64 * 2048;     // V^T: [hd][s]

  const int qA = p * 64 + qs * 32;
  const int qB = (31 - p) * 64 + qs * 32;
  const int R = 32 - p;  // kv tiles for the heavy member

  short8 qfA[4], qfB[4];
#pragma unroll
  for (int ks = 0; ks < 4; ++ks) {
    qfA[ks] = *(const short8*)(Qb + (size_t)(qA + l31) * 64 + ks * 16 + h * 8);
    qfB[ks] = *(const short8*)(Qb + (size_t)(qB + l31) * 64 + ks * 16 + h * 8);
  }

  f32x16 accA[2] = {}, accB[2] = {};
  float mA = -1e30f, mB = -1e30f, lA = 0.f, lB = 0.f;

  // staging: 256 threads x 16B covers half a tile per pass (2 passes K, 2 V)
  auto stage = [&](int buf, size_t kb) {
#pragma unroll
    for (int i = 0; i < 2; ++i) {
      const int row = i * 32 + (tid >> 3);
      const int sc = ((tid & 7) ^ (row & 7)) * 8;
      gload16(Kb + (kb + row) * 64 + sc, &Kl[buf][i * 2048 + wid * 512]);
      gload16(Vb + (size_t)row * 2048 + kb + sc, &Vl[buf][i * 2048 + wid * 512]);
    }
  };

  stage(0, 0);
  __syncthreads();

  for (int t = 0; t < R; ++t) {
    const int cur = t & 1;
    if (t + 1 < R) stage(cur ^ 1, (size_t)(t + 1) * 64);  // prefetch (T14)

    const int kvbase = t * 64 + kp * 32;
    const bool actB = kvbase <= qB + 31;
    const bool actA = kvbase <= qA + 31;  // actA implies actB (qA < qB)
    if (actB) {
      // K fragments (A-operand) and V^T fragments for this wave's kv sub
      short8 kf[4], vf[2][2];
      const int krow = kp * 32 + l31;
#pragma unroll
      for (int ks = 0; ks < 4; ++ks)
        kf[ks] = *(const short8*)((const char*)&Kl[cur][0] + krow * 128 +
                                  (((ks * 2 + h) ^ (krow & 7)) << 4));
#pragma unroll
      for (int n = 0; n < 2; ++n)
#pragma unroll
        for (int ks = 0; ks < 2; ++ks) {
          const int row = n * 32 + l31;
          vf[n][ks] = *(const short8*)((const char*)&Vl[cur][0] + row * 128 +
                                       (((kp * 4 + ks * 2 + h) ^ (row & 7)) << 4));
        }

      auto strip = [&](const short8(&qf)[4], f32x16(&acc)[2], float& m, float& l, int q0) {
        f32x16 sa = {};
#pragma unroll
        for (int ks = 0; ks < 4; ++ks)
          sa = __builtin_amdgcn_mfma_f32_32x32x16_bf16(kf[ks], qf[ks], sa, 0, 0, 0);
        if (kvbase == q0) {  // diagonal subtile
#pragma unroll
          for (int r = 0; r < 16; ++r) {
            const int kvr = (r & 3) + 8 * (r >> 2) + 4 * h;
            if (kvr > l31) sa[r] = -1e30f;
          }
        }
        float rm = fmaxf(fmaxf(fmaxf(sa[0], sa[1]), fmaxf(sa[2], sa[3])),
                         fmaxf(fmaxf(sa[4], sa[5]), fmaxf(sa[6], sa[7])));
        rm = fmaxf(rm, fmaxf(fmaxf(fmaxf(sa[8], sa[9]), fmaxf(sa[10], sa[11])),
                             fmaxf(fmaxf(sa[12], sa[13]), fmaxf(sa[14], sa[15]))));
        rm = fmaxf(rm, __shfl_xor(rm, 32));
        if (!__all(rm <= m + 5.0f)) {  // T13 defer-max (log2 units)
          const float mn = fmaxf(m, rm);
          const float corr = exp2f(m - mn);
          m = mn;
          l *= corr;
#pragma unroll
          for (int n = 0; n < 2; ++n)
#pragma unroll
            for (int r = 0; r < 16; ++r) acc[n][r] *= corr;
        }
#pragma unroll
        for (int r = 0; r < 16; ++r) sa[r] = exp2f(sa[r] - m);
        // row-sum (16 in-lane + cross-half partner has same q)
        float rs = (((sa[0] + sa[1]) + (sa[2] + sa[3])) + ((sa[4] + sa[5]) + (sa[6] + sa[7]))) +
                   (((sa[8] + sa[9]) + (sa[10] + sa[11])) + ((sa[12] + sa[13]) + (sa[14] + sa[15])));
        l += rs + __shfl_xor(rs, 32);
        // pack P^T pairs; build B-operand frags via cross-half exchange (T12)
        unsigned c[8], s[8];
#pragma unroll
        for (int i = 0; i < 8; ++i) c[i] = pack2(sa[2 * i], sa[2 * i + 1]);
#pragma unroll
        for (int i = 0; i < 8; ++i) s[i] = __shfl_xor(c[i], 32);
        u32x4 w0, w1;
        if (h == 0) {
          w0 = (u32x4){c[0], c[1], s[0], s[1]};
          w1 = (u32x4){c[4], c[5], s[4], s[5]};
        } else {
          w0 = (u32x4){s[2], s[3], c[2], c[3]};
          w1 = (u32x4){s[6], s[7], c[6], c[7]};
        }
        const short8 pk0 = __builtin_bit_cast(short8, w0);
        const short8 pk1 = __builtin_bit_cast(short8, w1);
#pragma unroll
        for (int n = 0; n < 2; ++n) {
          acc[n] = __builtin_amdgcn_mfma_f32_32x32x16_bf16(vf[n][0], pk0, acc[n], 0, 0, 0);
          acc[n] = __builtin_amdgcn_mfma_f32_32x32x16_bf16(vf[n][1], pk1, acc[n], 0, 0, 0);
        }
      };

      strip(qfB, accB, mB, lB, qB);
      if (actA) strip(qfA, accA, mA, lA, qA);
    }
    __syncthreads();
  }

  // ---- merge kv-parity partials (flash combine) and store ----
  // comb layout: [qs][strip][lane][36 floats]  (36*4=144B stride, 16B aligned)
  float* comb = (float*)smem;
  float* pA = comb + ((qs * 2 + 0) * 64 + lane) * 36;
  float* pB = comb + ((qs * 2 + 1) * 64 + lane) * 36;
  if (kp == 1) {
    pA[0] = mA; pA[1] = lA;
    pB[0] = mB; pB[1] = lB;
#pragma unroll
    for (int n = 0; n < 2; ++n)
#pragma unroll
      for (int r = 0; r < 16; ++r) {
        pA[2 + n * 16 + r] = accA[n][r];
        pB[2 + n * 16 + r] = accB[n][r];
      }
  }
  __syncthreads();
  if (kp == 0) {
    const int b = bh >> 4, hh = bh & 15;
    auto merge_store = [&](const float* pp, const f32x16(&acc)[2], float m0, float l0, int q0) {
      const float m1 = pp[0], l1 = pp[1];
      const float mn = fmaxf(m0, m1);
      const float c0 = exp2f(m0 - mn), c1 = exp2f(m1 - mn);
      const float inv = 1.0f / (l0 * c0 + l1 * c1);
      u16* rowp = Aout + (size_t)(b * 2048 + q0 + l31) * 1024 + hh * 64;
#pragma unroll
      for (int n = 0; n < 2; ++n)
#pragma unroll
        for (int r = 0; r < 16; r += 2) {
          const int hd = n * 32 + (r & 3) + 8 * (r >> 2) + 4 * h;
          const float v0 = (acc[n][r] * c0 + pp[2 + n * 16 + r] * c1) * inv;
          const float v1 = (acc[n][r + 1] * c0 + pp[2 + n * 16 + r + 1] * c1) * inv;
          *(unsigned*)(rowp + hd) = pack2(v0, v1);
        }
    };
    merge_store(pA, accA, mA, lA, qA);
    merge_store(pB, accB, mB, lB, qB);
  }
}

extern "C" void kernel_launch(void* const* d_in, const int* in_sizes, int n_in,
                              void* d_out, int out_size, void* d_ws, size_t ws_size,
                              hipStream_t stream) {
  const float* x = (const float*)d_in[0];
  const float* Wqkv = (const float*)d_in[1];
  const float* bqkv = (const float*)d_in[2];
  const float* Wout = (const float*)d_in[3];
  const float* bout = (const float*)d_in[4];

  char* ws = (char*)d_ws;
  u16* Xb = (u16*)(ws + 0);            // 8,388,608 B  (reused as Attn later)
  u16* WqkvT = (u16*)(ws + 8388608);   // 6,291,456 B
  u16* WoutT = (u16*)(ws + 14680064);  // 2,097,152 B
  u16* QKV = (u16*)(ws + 16777216);    // 25,165,824 B (Q, K, V^T)
  u16* Attn = Xb;

  cvt_x_kernel<<<4096, 256, 0, stream>>>(x, Xb, 4194304);
  tcvt_kernel<<<dim3(96, 32), dim3(32, 8), 0, stream>>>(Wqkv, WqkvT, 3072);
  tcvt_kernel<<<dim3(32, 32), dim3(32, 8), 0, stream>>>(Wout, WoutT, 1024);
  gemm_kernel<0><<<dim3(24, 32), 256, 0, stream>>>(Xb, WqkvT, bqkv, QKV);
  attn_kernel<<<dim3(16, 32), 256, 0, stream>>>(QKV, QKV + 4194304, QKV + 8388608, Attn);
  gemm_kernel<1><<<dim3(8, 32), 256, 0, stream>>>(Attn, WoutT, bout, d_out);
}

// Round 9
// 112.238 us; speedup vs baseline: 2.2923x; 1.0072x over previous
//
#include <hip/hip_runtime.h>
#include <hip/hip_bf16.h>

typedef __attribute__((ext_vector_type(8))) short short8;
typedef __attribute__((ext_vector_type(4))) short short4v;
typedef __attribute__((ext_vector_type(4))) float f32x4;
typedef __attribute__((ext_vector_type(16))) float f32x16;
typedef __attribute__((ext_vector_type(4))) unsigned int u32x4;
typedef unsigned short u16;

__device__ __forceinline__ u16 f2bf(float f) {
  __hip_bfloat16 h = __float2bfloat16(f);
  return __builtin_bit_cast(unsigned short, h);
}

__device__ __forceinline__ unsigned pack2(float lo, float hi) {
  return (unsigned)f2bf(lo) | ((unsigned)f2bf(hi) << 16);
}

__device__ __forceinline__ void gload16(const u16* g, u16* l) {
  __builtin_amdgcn_global_load_lds(
      (const __attribute__((address_space(1))) unsigned int*)g,
      (__attribute__((address_space(3))) unsigned int*)l, 16, 0, 0);
}

// ---------- x fp32 -> bf16 ----------
__global__ void cvt_x_kernel(const float* __restrict__ in, u16* __restrict__ out, int n) {
  int i = (blockIdx.x * blockDim.x + threadIdx.x) * 4;
  if (i >= n) return;
  float4 f = *(const float4*)(in + i);
  uint2 pk;
  pk.x = pack2(f.x, f.y);
  pk.y = pack2(f.z, f.w);
  *(uint2*)(out + i) = pk;
}

// ---------- W [1024][N] fp32 -> Wt [N][1024] bf16 ----------
__global__ void tcvt_kernel(const float* __restrict__ in, u16* __restrict__ out, int N) {
  __shared__ float tile[32][33];
  int n0 = blockIdx.x * 32, k0 = blockIdx.y * 32;
  int tx = threadIdx.x, ty = threadIdx.y;  // 32 x 8
#pragma unroll
  for (int r = 0; r < 4; ++r) {
    int k = ty + r * 8;
    tile[k][tx] = in[(size_t)(k0 + k) * N + n0 + tx];
  }
  __syncthreads();
#pragma unroll
  for (int r = 0; r < 4; ++r) {
    int n = ty + r * 8;
    out[(size_t)(n0 + n) * 1024 + k0 + tx] = f2bf(tile[tx][n]);
  }
}

// ---------- GEMM: C[128x128 tile] = A[M][1024] * Bt[N][1024]^T + bias ----------
// EPI 0: Q,K -> bf16 [b,h,s,64] (Q scaled by 0.125*log2e); V -> TRANSPOSED [b,h,hd,s]
// EPI 1: fp32 out [4096][1024] + bias
template <int EPI>
__global__ __launch_bounds__(256, 2) void gemm_kernel(const u16* __restrict__ A,
                                                      const u16* __restrict__ Bt,
                                                      const float* __restrict__ bias,
                                                      void* __restrict__ outp) {
  __shared__ u16 Al[128 * 64];
  __shared__ u16 Bl[128 * 64];
  const int tid = threadIdx.x;
  const int lane = tid & 63, wid = tid >> 6;
  const int l15 = lane & 15, lg = lane >> 4;
  const int wm = wid >> 1, wn = wid & 1;
  const int m0 = blockIdx.y * 128, n0 = blockIdx.x * 128;

  f32x4 acc[4][4] = {};

  for (int k0 = 0; k0 < 1024; k0 += 64) {
    __syncthreads();
#pragma unroll
    for (int i = 0; i < 4; ++i) {
      int p = i * 4096 + tid * 16;
      int row = p >> 7;
      int lslot = ((p >> 4) & 7) ^ (row & 7);
      gload16(A + (size_t)(m0 + row) * 1024 + k0 + lslot * 8, Al + i * 2048 + wid * 512);
      gload16(Bt + (size_t)(n0 + row) * 1024 + k0 + lslot * 8, Bl + i * 2048 + wid * 512);
    }
    __syncthreads();
#pragma unroll
    for (int ks = 0; ks < 2; ++ks) {
      short8 af[4], bfr[4];
#pragma unroll
      for (int m = 0; m < 4; ++m) {
        int row = wm * 64 + m * 16 + l15;
        af[m] = *(const short8*)((const char*)Al + row * 128 + (((ks * 4 + lg) ^ (row & 7)) << 4));
      }
#pragma unroll
      for (int n = 0; n < 4; ++n) {
        int row = wn * 64 + n * 16 + l15;
        bfr[n] = *(const short8*)((const char*)Bl + row * 128 + (((ks * 4 + lg) ^ (row & 7)) << 4));
      }
#pragma unroll
      for (int m = 0; m < 4; ++m)
#pragma unroll
        for (int n = 0; n < 4; ++n)
          acc[m][n] = __builtin_amdgcn_mfma_f32_16x16x32_bf16(af[m], bfr[n], acc[m][n], 0, 0, 0);
    }
  }

  if (EPI == 0) {
    u16* qkv = (u16*)outp;
#pragma unroll
    for (int m = 0; m < 4; ++m)
#pragma unroll
      for (int n = 0; n < 4; ++n) {
        const int gcol = n0 + wn * 64 + n * 16 + l15;
        const int which = gcol >> 10, dd = gcol & 1023;
        const int h = dd >> 6, hd = dd & 63;
        const float bb = bias[gcol];
        const int grow0 = m0 + wm * 64 + m * 16 + lg * 4;
        const int b = grow0 >> 11, s0 = grow0 & 2047;
        if (which == 2) {
          // V: store transposed [b,h,hd,s] — 4 consecutive s -> one 8B store
          short4v pk;
#pragma unroll
          for (int j = 0; j < 4; ++j) pk[j] = (short)f2bf(acc[m][n][j] + bb);
          *(short4v*)(qkv + (size_t)2 * 4194304 + ((size_t)(b * 16 + h) * 64 + hd) * 2048 + s0) = pk;
        } else {
          const float sc = (which == 0) ? 0.18033688011112042f : 1.0f;  // 1/sqrt(64)*log2e on Q
#pragma unroll
          for (int j = 0; j < 4; ++j) {
            float v = (acc[m][n][j] + bb) * sc;
            qkv[(size_t)which * 4194304 + ((size_t)(b * 16 + h) * 2048 + s0 + j) * 64 + hd] = f2bf(v);
          }
        }
      }
  } else {
    float* O = (float*)outp;
#pragma unroll
    for (int m = 0; m < 4; ++m)
#pragma unroll
      for (int n = 0; n < 4; ++n) {
        const int gcol = n0 + wn * 64 + n * 16 + l15;
        const float bb = bias[gcol];
#pragma unroll
        for (int j = 0; j < 4; ++j) {
          const int grow = m0 + wm * 64 + m * 16 + lg * 4 + j;
          O[(size_t)grow * 1024 + gcol] = acc[m][n][j] + bb;
        }
      }
  }
}

// ---------- causal flash attention, 32x32 MFMA, swapped QK^T, in-register P ----------
// Grid (16, 32). Block = 256 threads (4 waves). Block p handles 64-row q-tiles
// p and 31-p (complement pairing). Wave (qs=wid&1, kp=wid>>1): q-strip
// tile*64+qs*32 of BOTH tiles, kv-subtile parity kp of each staged 64-kv tile.
// Per-wave online-softmax partials merged at the end via LDS (flash combine).
// launch_bounds(256,2): 256-VGPR cap — (256,4) forced a 64-VGPR spill (R6).
// NO cross-lane P exchange: PV uses the relabeled k-slot map
// kappa(j,h) = 4h + (j&3) + 8*(j>>2), so P feeds the MFMA B-operand directly
// from pack2 output and V^T is read at matching kv offsets (2x ds_read_b64).
__global__ __launch_bounds__(256, 2) void attn_kernel(const u16* __restrict__ Q,
                                                      const u16* __restrict__ K,
                                                      const u16* __restrict__ VT,
                                                      u16* __restrict__ Aout) {
  const int bh = blockIdx.y;   // 0..31
  const int p = blockIdx.x;    // 0..15 -> pair (p, 31-p)
  const int tid = threadIdx.x, lane = tid & 63, wid = tid >> 6;
  const int l31 = lane & 31, h = lane >> 5;
  const int qs = wid & 1, kp = wid >> 1;

  __shared__ __align__(16) char smem[36864];
  u16(*Kl)[4096] = (u16(*)[4096])smem;             // [2][64*64] kv x hd, swizzled
  u16(*Vl)[4096] = (u16(*)[4096])(smem + 16384);   // [2][64*64] hd x kv, swizzled

  const u16* Qb = Q + (size_t)bh * 2048 * 64;
  const u16* Kb = K + (size_t)bh * 2048 * 64;
  const u16* Vb = VT + (size_t)bh * 64 * 2048;     // V^T: [hd][s]

  const int qA = p * 64 + qs * 32;
  const int qB = (31 - p) * 64 + qs * 32;
  const int R = 32 - p;  // kv tiles for the heavy member

  short8 qfA[4], qfB[4];
#pragma unroll
  for (int ks = 0; ks < 4; ++ks) {
    qfA[ks] = *(const short8*)(Qb + (size_t)(qA + l31) * 64 + ks * 16 + h * 8);
    qfB[ks] = *(const short8*)(Qb + (size_t)(qB + l31) * 64 + ks * 16 + h * 8);
  }

  f32x16 accA[2] = {}, accB[2] = {};
  float mA = -1e30f, mB = -1e30f, lA = 0.f, lB = 0.f;

  // staging: 256 threads x 16B covers half a tile per pass (2 passes K, 2 V)
  auto stage = [&](int buf, size_t kb) {
#pragma unroll
    for (int i = 0; i < 2; ++i) {
      const int row = i * 32 + (tid >> 3);
      const int sc = ((tid & 7) ^ (row & 7)) * 8;
      gload16(Kb + (kb + row) * 64 + sc, &Kl[buf][i * 2048 + wid * 512]);
      gload16(Vb + (size_t)row * 2048 + kb + sc, &Vl[buf][i * 2048 + wid * 512]);
    }
  };

  stage(0, 0);
  __syncthreads();

  for (int t = 0; t < R; ++t) {
    const int cur = t & 1;
    if (t + 1 < R) stage(cur ^ 1, (size_t)(t + 1) * 64);  // prefetch (T14)

    const int kvbase = t * 64 + kp * 32;
    const bool actB = kvbase <= qB + 31;
    const bool actA = kvbase <= qA + 31;  // actA implies actB (qA < qB)
    if (actB) {
      // K fragments (A-operand), natural layout
      short8 kf[4];
      const int krow = kp * 32 + l31;
#pragma unroll
      for (int ks = 0; ks < 4; ++ks)
        kf[ks] = *(const short8*)((const char*)&Kl[cur][0] + krow * 128 +
                                  (((ks * 2 + h) ^ (krow & 7)) << 4));
      // V^T fragments at kappa-ordered kv offsets: slots j=0..3 <- kv cb..cb+3,
      // j=4..7 <- kv cb+8..cb+11, where cb = kp*32 + ks*16 + 4h.
      short8 vf[2][2];
#pragma unroll
      for (int n = 0; n < 2; ++n) {
        const int row = n * 32 + l31;
        const int rx = row & 7;
        const char* base = (const char*)&Vl[cur][0] + row * 128;
#pragma unroll
        for (int ks = 0; ks < 2; ++ks) {
          const int cb = kp * 32 + ks * 16 + 4 * h;
          const int c2 = cb + 8;
          const short4v lo = *(const short4v*)(base + (((cb >> 3) ^ rx) << 4) + ((cb & 4) << 1));
          const short4v hi = *(const short4v*)(base + (((c2 >> 3) ^ rx) << 4) + ((c2 & 4) << 1));
          vf[n][ks] = (short8){lo[0], lo[1], lo[2], lo[3], hi[0], hi[1], hi[2], hi[3]};
        }
      }

      auto strip = [&](const short8(&qf)[4], f32x16(&acc)[2], float& m, float& l, int q0) {
        f32x16 sa = {};
        __builtin_amdgcn_s_setprio(1);
#pragma unroll
        for (int ks = 0; ks < 4; ++ks)
          sa = __builtin_amdgcn_mfma_f32_32x32x16_bf16(kf[ks], qf[ks], sa, 0, 0, 0);
        __builtin_amdgcn_s_setprio(0);
        if (kvbase == q0) {  // diagonal subtile
#pragma unroll
          for (int r = 0; r < 16; ++r) {
            const int kvr = (r & 3) + 8 * (r >> 2) + 4 * h;
            if (kvr > l31) sa[r] = -1e30f;
          }
        }
        // row max: max3-friendly triples (T17), then cross-half
        const float t0 = fmaxf(fmaxf(sa[0], sa[1]), sa[2]);
        const float t1 = fmaxf(fmaxf(sa[3], sa[4]), sa[5]);
        const float t2 = fmaxf(fmaxf(sa[6], sa[7]), sa[8]);
        const float t3 = fmaxf(fmaxf(sa[9], sa[10]), sa[11]);
        const float t4 = fmaxf(fmaxf(sa[12], sa[13]), sa[14]);
        float rm = fmaxf(fmaxf(fmaxf(t0, t1), t2), fmaxf(fmaxf(t3, t4), sa[15]));
        rm = fmaxf(rm, __shfl_xor(rm, 32));
        if (!__all(rm <= m + 5.0f)) {  // T13 defer-max (log2 units)
          const float mn = fmaxf(m, rm);
          const float corr = exp2f(m - mn);
          m = mn;
          l *= corr;
#pragma unroll
          for (int n = 0; n < 2; ++n)
#pragma unroll
            for (int r = 0; r < 16; ++r) acc[n][r] *= corr;
        }
#pragma unroll
        for (int r = 0; r < 16; ++r) sa[r] = exp2f(sa[r] - m);
        // row-sum (16 in-lane, then cross-half)
        float rs = (((sa[0] + sa[1]) + (sa[2] + sa[3])) + ((sa[4] + sa[5]) + (sa[6] + sa[7]))) +
                   (((sa[8] + sa[9]) + (sa[10] + sa[11])) + ((sa[12] + sa[13]) + (sa[14] + sa[15])));
        l += rs + __shfl_xor(rs, 32);
        // P in natural kappa order -> PV B-operand directly, no exchange
        unsigned c[8];
#pragma unroll
        for (int i = 0; i < 8; ++i) c[i] = pack2(sa[2 * i], sa[2 * i + 1]);
        const short8 pk0 = __builtin_bit_cast(short8, (u32x4){c[0], c[1], c[2], c[3]});
        const short8 pk1 = __builtin_bit_cast(short8, (u32x4){c[4], c[5], c[6], c[7]});
        __builtin_amdgcn_s_setprio(1);
#pragma unroll
        for (int n = 0; n < 2; ++n) {
          acc[n] = __builtin_amdgcn_mfma_f32_32x32x16_bf16(vf[n][0], pk0, acc[n], 0, 0, 0);
          acc[n] = __builtin_amdgcn_mfma_f32_32x32x16_bf16(vf[n][1], pk1, acc[n], 0, 0, 0);
        }
        __builtin_amdgcn_s_setprio(0);
      };

      strip(qfB, accB, mB, lB, qB);
      if (actA) strip(qfA, accA, mA, lA, qA);
    }
    __syncthreads();
  }

  // ---- merge kv-parity partials (flash combine) and store ----
  // comb layout: [qs][strip][lane][36 floats]  (36*4=144B stride, 16B aligned)
  float* comb = (float*)smem;
  float* pA = comb + ((qs * 2 + 0) * 64 + lane) * 36;
  float* pB = comb + ((qs * 2 + 1) * 64 + lane) * 36;
  if (kp == 1) {
    pA[0] = mA; pA[1] = lA;
    pB[0] = mB; pB[1] = lB;
#pragma unroll
    for (int n = 0; n < 2; ++n)
#pragma unroll
      for (int r = 0; r < 16; ++r) {
        pA[2 + n * 16 + r] = accA[n][r];
        pB[2 + n * 16 + r] = accB[n][r];
      }
  }
  __syncthreads();
  if (kp == 0) {
    const int b = bh >> 4, hh = bh & 15;
    auto merge_store = [&](const float* pp, const f32x16(&acc)[2], float m0, float l0, int q0) {
      const float m1 = pp[0], l1 = pp[1];
      const float mn = fmaxf(m0, m1);
      const float c0 = exp2f(m0 - mn), c1 = exp2f(m1 - mn);
      const float inv = 1.0f / (l0 * c0 + l1 * c1);
      u16* rowp = Aout + (size_t)(b * 2048 + q0 + l31) * 1024 + hh * 64;
#pragma unroll
      for (int n = 0; n < 2; ++n)
#pragma unroll
        for (int r = 0; r < 16; r += 2) {
          const int hd = n * 32 + (r & 3) + 8 * (r >> 2) + 4 * h;
          const float v0 = (acc[n][r] * c0 + pp[2 + n * 16 + r] * c1) * inv;
          const float v1 = (acc[n][r + 1] * c0 + pp[2 + n * 16 + r + 1] * c1) * inv;
          *(unsigned*)(rowp + hd) = pack2(v0, v1);
        }
    };
    merge_store(pA, accA, mA, lA, qA);
    merge_store(pB, accB, mB, lB, qB);
  }
}

extern "C" void kernel_launch(void* const* d_in, const int* in_sizes, int n_in,
                              void* d_out, int out_size, void* d_ws, size_t ws_size,
                              hipStream_t stream) {
  const float* x = (const float*)d_in[0];
  const float* Wqkv = (const float*)d_in[1];
  const float* bqkv = (const float*)d_in[2];
  const float* Wout = (const float*)d_in[3];
  const float* bout = (const float*)d_in[4];

  char* ws = (char*)d_ws;
  u16* Xb = (u16*)(ws + 0);            // 8,388,608 B  (reused as Attn later)
  u16* WqkvT = (u16*)(ws + 8388608);   // 6,291,456 B
  u16* WoutT = (u16*)(ws + 14680064);  // 2,097,152 B
  u16* QKV = (u16*)(ws + 16777216);    // 25,165,824 B (Q, K, V^T)
  u16* Attn = Xb;

  cvt_x_kernel<<<4096, 256, 0, stream>>>(x, Xb, 4194304);
  tcvt_kernel<<<dim3(96, 32), dim3(32, 8), 0, stream>>>(Wqkv, WqkvT, 3072);
  tcvt_kernel<<<dim3(32, 32), dim3(32, 8), 0, stream>>>(Wout, WoutT, 1024);
  gemm_kernel<0><<<dim3(24, 32), 256, 0, stream>>>(Xb, WqkvT, bqkv, QKV);
  attn_kernel<<<dim3(16, 32), 256, 0, stream>>>(QKV, QKV + 4194304, QKV + 8388608, Attn);
  gemm_kernel<1><<<dim3(8, 32), 256, 0, stream>>>(Attn, WoutT, bout, d_out);
}

// Round 10
// 110.393 us; speedup vs baseline: 2.3306x; 1.0167x over previous
//
#include <hip/hip_runtime.h>
#include <hip/hip_bf16.h>

typedef __attribute__((ext_vector_type(8))) short short8;
typedef __attribute__((ext_vector_type(4))) short short4v;
typedef __attribute__((ext_vector_type(4))) float f32x4;
typedef __attribute__((ext_vector_type(16))) float f32x16;
typedef __attribute__((ext_vector_type(4))) unsigned int u32x4;
typedef unsigned short u16;

__device__ __forceinline__ u16 f2bf(float f) {
  __hip_bfloat16 h = __float2bfloat16(f);
  return __builtin_bit_cast(unsigned short, h);
}

__device__ __forceinline__ unsigned pack2(float lo, float hi) {
  return (unsigned)f2bf(lo) | ((unsigned)f2bf(hi) << 16);
}

__device__ __forceinline__ void gload16(const u16* g, u16* l) {
  __builtin_amdgcn_global_load_lds(
      (const __attribute__((address_space(1))) unsigned int*)g,
      (__attribute__((address_space(3))) unsigned int*)l, 16, 0, 0);
}

// ---------- x fp32 -> bf16 ----------
__global__ void cvt_x_kernel(const float* __restrict__ in, u16* __restrict__ out, int n) {
  int i = (blockIdx.x * blockDim.x + threadIdx.x) * 4;
  if (i >= n) return;
  float4 f = *(const float4*)(in + i);
  uint2 pk;
  pk.x = pack2(f.x, f.y);
  pk.y = pack2(f.z, f.w);
  *(uint2*)(out + i) = pk;
}

// ---------- W [1024][N] fp32 -> Wt [N][1024] bf16 ----------
__global__ void tcvt_kernel(const float* __restrict__ in, u16* __restrict__ out, int N) {
  __shared__ float tile[32][33];
  int n0 = blockIdx.x * 32, k0 = blockIdx.y * 32;
  int tx = threadIdx.x, ty = threadIdx.y;  // 32 x 8
#pragma unroll
  for (int r = 0; r < 4; ++r) {
    int k = ty + r * 8;
    tile[k][tx] = in[(size_t)(k0 + k) * N + n0 + tx];
  }
  __syncthreads();
#pragma unroll
  for (int r = 0; r < 4; ++r) {
    int n = ty + r * 8;
    out[(size_t)(n0 + n) * 1024 + k0 + tx] = f2bf(tile[tx][n]);
  }
}

// ---------- GEMM: C[128x128 tile] = A[M][1024] * Bt[N][1024]^T + bias ----------
// EPI 0: Q,K -> bf16 [b,h,s,64] (Q scaled by 0.125*log2e);
//        V -> TRANSPOSED [b,h,hd,s'] with kappa block permutation:
//        within each 16-kv group, 4-blocks stored as [B0,B2,B1,B3] so attn's
//        PV operand is one contiguous b128 read matching P's natural order.
// EPI 1: fp32 out [4096][1024] + bias
template <int EPI>
__global__ __launch_bounds__(256, 2) void gemm_kernel(const u16* __restrict__ A,
                                                      const u16* __restrict__ Bt,
                                                      const float* __restrict__ bias,
                                                      void* __restrict__ outp) {
  __shared__ u16 Al[128 * 64];
  __shared__ u16 Bl[128 * 64];
  const int tid = threadIdx.x;
  const int lane = tid & 63, wid = tid >> 6;
  const int l15 = lane & 15, lg = lane >> 4;
  const int wm = wid >> 1, wn = wid & 1;
  const int m0 = blockIdx.y * 128, n0 = blockIdx.x * 128;

  f32x4 acc[4][4] = {};

  for (int k0 = 0; k0 < 1024; k0 += 64) {
    __syncthreads();
#pragma unroll
    for (int i = 0; i < 4; ++i) {
      int p = i * 4096 + tid * 16;
      int row = p >> 7;
      int lslot = ((p >> 4) & 7) ^ (row & 7);
      gload16(A + (size_t)(m0 + row) * 1024 + k0 + lslot * 8, Al + i * 2048 + wid * 512);
      gload16(Bt + (size_t)(n0 + row) * 1024 + k0 + lslot * 8, Bl + i * 2048 + wid * 512);
    }
    __syncthreads();
#pragma unroll
    for (int ks = 0; ks < 2; ++ks) {
      short8 af[4], bfr[4];
#pragma unroll
      for (int m = 0; m < 4; ++m) {
        int row = wm * 64 + m * 16 + l15;
        af[m] = *(const short8*)((const char*)Al + row * 128 + (((ks * 4 + lg) ^ (row & 7)) << 4));
      }
#pragma unroll
      for (int n = 0; n < 4; ++n) {
        int row = wn * 64 + n * 16 + l15;
        bfr[n] = *(const short8*)((const char*)Bl + row * 128 + (((ks * 4 + lg) ^ (row & 7)) << 4));
      }
#pragma unroll
      for (int m = 0; m < 4; ++m)
#pragma unroll
        for (int n = 0; n < 4; ++n)
          acc[m][n] = __builtin_amdgcn_mfma_f32_16x16x32_bf16(af[m], bfr[n], acc[m][n], 0, 0, 0);
    }
  }

  if (EPI == 0) {
    u16* qkv = (u16*)outp;
#pragma unroll
    for (int m = 0; m < 4; ++m)
#pragma unroll
      for (int n = 0; n < 4; ++n) {
        const int gcol = n0 + wn * 64 + n * 16 + l15;
        const int which = gcol >> 10, dd = gcol & 1023;
        const int h = dd >> 6, hd = dd & 63;
        const float bb = bias[gcol];
        const int grow0 = m0 + wm * 64 + m * 16 + lg * 4;
        const int b = grow0 >> 11, s0 = grow0 & 2047;
        if (which == 2) {
          // V^T with kappa 4-block permutation: block 1 <-> block 2 per 16-group
          const int bsub = (s0 >> 2) & 3;
          const int bper = (bsub == 1) ? 2 : (bsub == 2) ? 1 : bsub;
          const int s0p = (s0 & ~15) | (bper << 2);
          short4v pk;
#pragma unroll
          for (int j = 0; j < 4; ++j) pk[j] = (short)f2bf(acc[m][n][j] + bb);
          *(short4v*)(qkv + (size_t)2 * 4194304 + ((size_t)(b * 16 + h) * 64 + hd) * 2048 + s0p) = pk;
        } else {
          const float sc = (which == 0) ? 0.18033688011112042f : 1.0f;  // 1/sqrt(64)*log2e on Q
#pragma unroll
          for (int j = 0; j < 4; ++j) {
            float v = (acc[m][n][j] + bb) * sc;
            qkv[(size_t)which * 4194304 + ((size_t)(b * 16 + h) * 2048 + s0 + j) * 64 + hd] = f2bf(v);
          }
        }
      }
  } else {
    float* O = (float*)outp;
#pragma unroll
    for (int m = 0; m < 4; ++m)
#pragma unroll
      for (int n = 0; n < 4; ++n) {
        const int gcol = n0 + wn * 64 + n * 16 + l15;
        const float bb = bias[gcol];
#pragma unroll
        for (int j = 0; j < 4; ++j) {
          const int grow = m0 + wm * 64 + m * 16 + lg * 4 + j;
          O[(size_t)grow * 1024 + gcol] = acc[m][n][j] + bb;
        }
      }
  }
}

// ---------- causal flash attention, 32x32 MFMA, swapped QK^T, in-register P ----------
// Grid (16, 32). Block = 256 threads (4 waves). Block p handles 64-row q-tiles
// p and 31-p (complement pairing). Wave (qs=wid&1, kp=wid>>1): q-strip
// tile*64+qs*32 of BOTH tiles, kv-subtile parity kp of each staged 64-kv tile.
// Per-wave online-softmax partials merged at the end via LDS (flash combine).
// launch_bounds(256,2): 256-VGPR cap — (256,4) forced a 64-VGPR spill (R6).
// P feeds PV directly (kappa order baked into V^T's global layout by the QKV
// epilogue) — no cross-lane exchange, single b128 V read.
// Strips interleaved: QK^T_A issues behind QK^T_B; PV_B overlaps softmax_A.
__global__ __launch_bounds__(256, 2) void attn_kernel(const u16* __restrict__ Q,
                                                      const u16* __restrict__ K,
                                                      const u16* __restrict__ VT,
                                                      u16* __restrict__ Aout) {
  const int bh = blockIdx.y;   // 0..31
  const int p = blockIdx.x;    // 0..15 -> pair (p, 31-p)
  const int tid = threadIdx.x, lane = tid & 63, wid = tid >> 6;
  const int l31 = lane & 31, h = lane >> 5;
  const int qs = wid & 1, kp = wid >> 1;

  __shared__ __align__(16) char smem[36864];
  u16(*Kl)[4096] = (u16(*)[4096])smem;             // [2][64*64] kv x hd, swizzled
  u16(*Vl)[4096] = (u16(*)[4096])(smem + 16384);   // [2][64*64] hd x kv', swizzled

  const u16* Qb = Q + (size_t)bh * 2048 * 64;
  const u16* Kb = K + (size_t)bh * 2048 * 64;
  const u16* Vb = VT + (size_t)bh * 64 * 2048;     // V^T: [hd][s'] (kappa-permuted)

  const int qA = p * 64 + qs * 32;
  const int qB = (31 - p) * 64 + qs * 32;
  const int R = 32 - p;  // kv tiles for the heavy member

  short8 qfA[4], qfB[4];
#pragma unroll
  for (int ks = 0; ks < 4; ++ks) {
    qfA[ks] = *(const short8*)(Qb + (size_t)(qA + l31) * 64 + ks * 16 + h * 8);
    qfB[ks] = *(const short8*)(Qb + (size_t)(qB + l31) * 64 + ks * 16 + h * 8);
  }

  f32x16 accA[2] = {}, accB[2] = {};
  float mA = -1e30f, mB = -1e30f, lA = 0.f, lB = 0.f;

  // staging: 256 threads x 16B covers half a tile per pass (2 passes K, 2 V)
  auto stage = [&](int buf, size_t kb) {
#pragma unroll
    for (int i = 0; i < 2; ++i) {
      const int row = i * 32 + (tid >> 3);
      const int sc = ((tid & 7) ^ (row & 7)) * 8;
      gload16(Kb + (kb + row) * 64 + sc, &Kl[buf][i * 2048 + wid * 512]);
      gload16(Vb + (size_t)row * 2048 + kb + sc, &Vl[buf][i * 2048 + wid * 512]);
    }
  };

  stage(0, 0);
  __syncthreads();

  for (int t = 0; t < R; ++t) {
    const int cur = t & 1;
    if (t + 1 < R) stage(cur ^ 1, (size_t)(t + 1) * 64);  // prefetch (T14)

    const int kvbase = t * 64 + kp * 32;
    const bool actB = kvbase <= qB + 31;
    const bool actA = kvbase <= qA + 31;  // actA implies actB (qA < qB)
    if (actB) {
      // K fragments (A-operand) and V^T fragments (kappa order in memory)
      short8 kf[4], vf[2][2];
      const int krow = kp * 32 + l31;
#pragma unroll
      for (int ks = 0; ks < 4; ++ks)
        kf[ks] = *(const short8*)((const char*)&Kl[cur][0] + krow * 128 +
                                  (((ks * 2 + h) ^ (krow & 7)) << 4));
#pragma unroll
      for (int n = 0; n < 2; ++n)
#pragma unroll
        for (int ks = 0; ks < 2; ++ks) {
          const int row = n * 32 + l31;
          vf[n][ks] = *(const short8*)((const char*)&Vl[cur][0] + row * 128 +
                                       (((kp * 4 + ks * 2 + h) ^ (row & 7)) << 4));
        }

      // both QK^T chains issued back-to-back: A's chain hides B's latency
      f32x16 saB = {}, saA = {};
      __builtin_amdgcn_s_setprio(1);
#pragma unroll
      for (int ks = 0; ks < 4; ++ks)
        saB = __builtin_amdgcn_mfma_f32_32x32x16_bf16(kf[ks], qfB[ks], saB, 0, 0, 0);
      if (actA) {
#pragma unroll
        for (int ks = 0; ks < 4; ++ks)
          saA = __builtin_amdgcn_mfma_f32_32x32x16_bf16(kf[ks], qfA[ks], saA, 0, 0, 0);
      }
      __builtin_amdgcn_s_setprio(0);

      auto finish = [&](f32x16& sa, f32x16(&acc)[2], float& m, float& l, int q0) {
        if (kvbase == q0) {  // diagonal subtile
#pragma unroll
          for (int r = 0; r < 16; ++r) {
            const int kvr = (r & 3) + 8 * (r >> 2) + 4 * h;
            if (kvr > l31) sa[r] = -1e30f;
          }
        }
        // row max: max3-friendly triples (T17), then cross-half
        const float t0 = fmaxf(fmaxf(sa[0], sa[1]), sa[2]);
        const float t1 = fmaxf(fmaxf(sa[3], sa[4]), sa[5]);
        const float t2 = fmaxf(fmaxf(sa[6], sa[7]), sa[8]);
        const float t3 = fmaxf(fmaxf(sa[9], sa[10]), sa[11]);
        const float t4 = fmaxf(fmaxf(sa[12], sa[13]), sa[14]);
        float rm = fmaxf(fmaxf(fmaxf(t0, t1), t2), fmaxf(fmaxf(t3, t4), sa[15]));
        rm = fmaxf(rm, __shfl_xor(rm, 32));
        if (!__all(rm <= m + 5.0f)) {  // T13 defer-max (log2 units)
          const float mn = fmaxf(m, rm);
          const float corr = exp2f(m - mn);
          m = mn;
          l *= corr;
#pragma unroll
          for (int n = 0; n < 2; ++n)
#pragma unroll
            for (int r = 0; r < 16; ++r) acc[n][r] *= corr;
        }
#pragma unroll
        for (int r = 0; r < 16; ++r) sa[r] = exp2f(sa[r] - m);
        // row-sum (16 in-lane, then cross-half)
        float rs = (((sa[0] + sa[1]) + (sa[2] + sa[3])) + ((sa[4] + sa[5]) + (sa[6] + sa[7]))) +
                   (((sa[8] + sa[9]) + (sa[10] + sa[11])) + ((sa[12] + sa[13]) + (sa[14] + sa[15])));
        l += rs + __shfl_xor(rs, 32);
        // P in natural kappa order -> PV B-operand directly
        unsigned c[8];
#pragma unroll
        for (int i = 0; i < 8; ++i) c[i] = pack2(sa[2 * i], sa[2 * i + 1]);
        const short8 pk0 = __builtin_bit_cast(short8, (u32x4){c[0], c[1], c[2], c[3]});
        const short8 pk1 = __builtin_bit_cast(short8, (u32x4){c[4], c[5], c[6], c[7]});
        __builtin_amdgcn_s_setprio(1);
#pragma unroll
        for (int n = 0; n < 2; ++n) {
          acc[n] = __builtin_amdgcn_mfma_f32_32x32x16_bf16(vf[n][0], pk0, acc[n], 0, 0, 0);
          acc[n] = __builtin_amdgcn_mfma_f32_32x32x16_bf16(vf[n][1], pk1, acc[n], 0, 0, 0);
        }
        __builtin_amdgcn_s_setprio(0);
      };

      finish(saB, accB, mB, lB, qB);       // PV_B overlaps softmax_A below
      if (actA) finish(saA, accA, mA, lA, qA);
    }
    __syncthreads();
  }

  // ---- merge kv-parity partials (flash combine) and store ----
  // comb layout: [qs][strip][lane][36 floats]  (36*4=144B stride, 16B aligned)
  float* comb = (float*)smem;
  float* pA = comb + ((qs * 2 + 0) * 64 + lane) * 36;
  float* pB = comb + ((qs * 2 + 1) * 64 + lane) * 36;
  if (kp == 1) {
    pA[0] = mA; pA[1] = lA;
    pB[0] = mB; pB[1] = lB;
#pragma unroll
    for (int n = 0; n < 2; ++n)
#pragma unroll
      for (int r = 0; r < 16; ++r) {
        pA[2 + n * 16 + r] = accA[n][r];
        pB[2 + n * 16 + r] = accB[n][r];
      }
  }
  __syncthreads();
  if (kp == 0) {
    const int b = bh >> 4, hh = bh & 15;
    auto merge_store = [&](const float* pp, const f32x16(&acc)[2], float m0, float l0, int q0) {
      const float m1 = pp[0], l1 = pp[1];
      const float mn = fmaxf(m0, m1);
      const float c0 = exp2f(m0 - mn), c1 = exp2f(m1 - mn);
      const float inv = 1.0f / (l0 * c0 + l1 * c1);
      u16* rowp = Aout + (size_t)(b * 2048 + q0 + l31) * 1024 + hh * 64;
#pragma unroll
      for (int n = 0; n < 2; ++n)
#pragma unroll
        for (int r = 0; r < 16; r += 2) {
          const int hd = n * 32 + (r & 3) + 8 * (r >> 2) + 4 * h;
          const float v0 = (acc[n][r] * c0 + pp[2 + n * 16 + r] * c1) * inv;
          const float v1 = (acc[n][r + 1] * c0 + pp[2 + n * 16 + r + 1] * c1) * inv;
          *(unsigned*)(rowp + hd) = pack2(v0, v1);
        }
    };
    merge_store(pA, accA, mA, lA, qA);
    merge_store(pB, accB, mB, lB, qB);
  }
}

extern "C" void kernel_launch(void* const* d_in, const int* in_sizes, int n_in,
                              void* d_out, int out_size, void* d_ws, size_t ws_size,
                              hipStream_t stream) {
  const float* x = (const float*)d_in[0];
  const float* Wqkv = (const float*)d_in[1];
  const float* bqkv = (const float*)d_in[2];
  const float* Wout = (const float*)d_in[3];
  const float* bout = (const float*)d_in[4];

  char* ws = (char*)d_ws;
  u16* Xb = (u16*)(ws + 0);            // 8,388,608 B  (reused as Attn later)
  u16* WqkvT = (u16*)(ws + 8388608);   // 6,291,456 B
  u16* WoutT = (u16*)(ws + 14680064);  // 2,097,152 B
  u16* QKV = (u16*)(ws + 16777216);    // 25,165,824 B (Q, K, V^T kappa-permuted)
  u16* Attn = Xb;

  cvt_x_kernel<<<4096, 256, 0, stream>>>(x, Xb, 4194304);
  tcvt_kernel<<<dim3(96, 32), dim3(32, 8), 0, stream>>>(Wqkv, WqkvT, 3072);
  tcvt_kernel<<<dim3(32, 32), dim3(32, 8), 0, stream>>>(Wout, WoutT, 1024);
  gemm_kernel<0><<<dim3(24, 32), 256, 0, stream>>>(Xb, WqkvT, bqkv, QKV);
  attn_kernel<<<dim3(16, 32), 256, 0, stream>>>(QKV, QKV + 4194304, QKV + 8388608, Attn);
  gemm_kernel<1><<<dim3(8, 32), 256, 0, stream>>>(Attn, WoutT, bout, d_out);
}